// Round 3
// baseline (378.493 us; speedup 1.0000x reference)
//
#include <hip/hip_runtime.h>
#include <hip/hip_bf16.h>
#include <stdint.h>

// RWKV TimeMixing: N=8, T=2048, C=1024.
// Round 8: GEMMs restructured for 2-blocks/CU desync overlap: 256-thread/4-wave
// blocks, 256x128 tile (wave 128x64, acc[8][4]), BK=32, THREE 24KB LDS buffers
// (72KB/block -> 2 blocks/CU; ~220 unified regs -> 2 waves/SIMD OK).
// 2-tile-deep prefetch, counted vmcnt(6) at every tile boundary (no drain in
// steady state). One block's ds_read/barrier window overlaps the other block's
// MFMA window via HW wave scheduling (independent barriers). XCD decode kept.

typedef float f4 __attribute__((ext_vector_type(4)));
typedef short bh8 __attribute__((ext_vector_type(8)));
typedef unsigned int u32;
typedef unsigned short u16;

__device__ __forceinline__ u32 cvt2bf(float a, float b) {
    __hip_bfloat162 h = __float22bfloat162_rn(make_float2(a, b));
    u32 u; __builtin_memcpy(&u, &h, 4); return u;
}
__device__ __forceinline__ float b2f(u16 u) {
    u32 x = (u32)u << 16; float f; __builtin_memcpy(&f, &x, 4); return f;
}
__device__ __forceinline__ u16 f2b(float f) {
    __hip_bfloat16 h = __float2bfloat16(f);
    u16 u; __builtin_memcpy(&u, &h, 2); return u;
}
__device__ __forceinline__ void gld_lds16(const void* g, void* l) {
    __builtin_amdgcn_global_load_lds(
        (const __attribute__((address_space(1))) u32*)g,
        (__attribute__((address_space(3))) u32*)l, 16, 0, 0);
}

#define BAR() __builtin_amdgcn_s_barrier()

// ---------------------------------------------------------------------------
// gemm_ts<EPI>: C(16384xN) = A(16384x1024) @ B(Nx1024)^T, bf16 MFMA.
// EPI=0: bf16 out +bias, sigmoid on proj 2 (K/V/R merged via grid).
// EPI=1: f32 out, no bias.
// Tile 256x128, BK=32. LDS buffer = A[256][32] (16KB) + B[128][32] (8KB).
// Row = 4 chunks of 16B; phys chunk = logical ^ ((row&3)^((row>>2)&3)):
// uniform 2 lanes/bank on ds_read_b128 (free) and q/w-independent source
// swizzle for linear global_load_lds staging.
// Per K-tile t: read buf[t%3], ph1 stages tile t+2 into buf[(t+2)%3] (legal:
// its last reader was tile t-1, separated by the t-1/t boundary barrier).
// Boundary: vmcnt(6) retires t+1's 6 loads (issued 2 tiles ago), leaves t+2's
// 6 in flight. Phases: ph1 {8 ds_read + 6 gld_lds; BAR lgkm0 16 MFMA} BAR
//                     ph2 {4 ds_read; BAR lgkm0 16 MFMA vmcnt BAR}.
// ---------------------------------------------------------------------------

#define PH16(I0) \
  BAR(); \
  asm volatile("s_waitcnt lgkmcnt(0)" ::: "memory"); \
  __builtin_amdgcn_s_setprio(1); \
  _Pragma("unroll") for (int i = 0; i < 4; i++) \
  _Pragma("unroll") for (int j = 0; j < 4; j++) \
    acc[(I0)+i][j] = __builtin_amdgcn_mfma_f32_16x16x32_bf16( \
        af[i], bf[j], acc[(I0)+i][j], 0, 0, 0); \
  __builtin_amdgcn_s_setprio(0);

#define GB(CA, CB, NA, NB, KKN, STG, VM) do { \
  bh8 af[4], bf[4]; \
  _Pragma("unroll") for (int i = 0; i < 4; i++) af[i] = *(const bh8*)((CA) + apo + i * 512); \
  _Pragma("unroll") for (int j = 0; j < 4; j++) bf[j] = *(const bh8*)((CB) + bpo + j * 512); \
  if (STG) { \
    _Pragma("unroll") for (int q = 0; q < 4; q++) \
      gld_lds16(gA + sAoff + q * 65536 + (KKN), (NA) + q * 2048 + w * 512); \
    _Pragma("unroll") for (int h = 0; h < 2; h++) \
      gld_lds16(gB + sAoff + h * 65536 + (KKN), (NB) + h * 2048 + w * 512); \
  } \
  PH16(0); \
  BAR(); \
  _Pragma("unroll") for (int i = 0; i < 4; i++) af[i] = *(const bh8*)((CA) + apo + (4 + i) * 512); \
  PH16(4); \
  asm volatile("s_waitcnt vmcnt(" VM ")" ::: "memory"); \
  BAR(); \
} while (0)

template<int EPI>
__global__ __launch_bounds__(256, 2) void gemm_ts(
    const u16* __restrict__ Ag, const u16* __restrict__ Bg, const float* __restrict__ bias,
    u16* __restrict__ Kb, u16* __restrict__ Vb, u16* __restrict__ SRb, float* __restrict__ Yf)
{
    __shared__ __align__(16) char pool[73728];   // 3 x 24KB; epilogue <= 35KB
    u16* A0 = (u16*)pool;          u16* B0 = A0 + 8192;
    u16* A1 = (u16*)(pool + 24576); u16* B1 = A1 + 8192;
    u16* A2 = (u16*)(pool + 49152); u16* B2 = A2 + 8192;

    // XCD-locality decode: xcd = bid&7; XCD x owns m-band [x*8, x*8+8);
    // consecutive slots share the same A 256-row panel (nt innermost).
    const int bid = blockIdx.x;
    const int xcd = bid & 7;
    const int s   = bid >> 3;
    int p, mt, nt;
    if (EPI == 0) { p = s >> 6; int r = s & 63; nt = r & 7; mt = xcd * 8 + (r >> 3); }
    else          { p = 0;                      nt = s & 7; mt = xcd * 8 + (s >> 3); }
    const int n0 = nt * 128;
    const int m0 = mt * 256;

    const u16* gA = Ag + (size_t)m0 * 1024;
    const u16* gB = Bg + (EPI == 0 ? (size_t)p * 1048576 : 0) + (size_t)n0 * 1024;

    const int tid  = threadIdx.x;
    const int w    = tid >> 6;
    const int lane = tid & 63;
    const int wm = (w >> 1) * 128, wn = (w & 1) * 64;
    const int fr = lane & 15, quad = lane >> 4;
    // frag-read chunk: phys = quad ^ (fr&3) ^ ((fr>>2)&3)  (row-index bits fold out)
    const int cs  = (quad ^ ((fr ^ (fr >> 2)) & 3)) * 8;
    const int apo = (wm + fr) * 32 + cs;
    const int bpo = (wn + fr) * 32 + cs;

    // staging: per issue, wave w covers rows w*16+(lane>>2), slot lane&3;
    // source chunk = slot ^ (row&3) ^ ((row>>2)&3) -> lane-only expression.
    const int sAoff = (w * 16 + (lane >> 2)) * 1024 +
                      (((lane & 3) ^ ((lane >> 2) & 3) ^ ((lane >> 4) & 3))) * 8;

    f4 acc[8][4];
#pragma unroll
    for (int i = 0; i < 8; i++)
#pragma unroll
        for (int j = 0; j < 4; j++) { f4 z = {0.f, 0.f, 0.f, 0.f}; acc[i][j] = z; }

    // prologue: stage tiles 0 and 1; counted wait retires tile 0 only.
#pragma unroll
    for (int q = 0; q < 4; q++) gld_lds16(gA + sAoff + q * 65536, A0 + q * 2048 + w * 512);
#pragma unroll
    for (int h = 0; h < 2; h++) gld_lds16(gB + sAoff + h * 65536, B0 + h * 2048 + w * 512);
#pragma unroll
    for (int q = 0; q < 4; q++) gld_lds16(gA + sAoff + q * 65536 + 32, A1 + q * 2048 + w * 512);
#pragma unroll
    for (int h = 0; h < 2; h++) gld_lds16(gB + sAoff + h * 65536 + 32, B1 + h * 2048 + w * 512);
    asm volatile("s_waitcnt vmcnt(6)" ::: "memory");
    BAR();

    for (int t = 0; t < 30; t += 3) {
        GB(A0, B0, A2, B2, (t + 2) * 32, 1, "6");
        GB(A1, B1, A0, B0, (t + 3) * 32, 1, "6");
        GB(A2, B2, A1, B1, (t + 4) * 32, 1, "6");
    }
    GB(A0, B0, A2, B2, 0, 0, "0");   // t=30: wait tile 31's loads
    GB(A1, B1, A2, B2, 0, 0, "0");   // t=31

    // ---------------- epilogue ----------------
    if constexpr (EPI == 0) {
        const int batch = m0 >> 11;
        float bv[4];
#pragma unroll
        for (int j = 0; j < 4; j++) bv[j] = bias[p * 8192 + batch * 1024 + n0 + wn + j * 16 + fr];
        u16* S = (u16*)pool;                     // [128][136] bf16 per half
        u16* Y = p == 0 ? Kb : (p == 1 ? Vb : SRb);
#pragma unroll
        for (int h = 0; h < 2; h++) {
            __syncthreads();
            if ((w >> 1) == h) {
#pragma unroll
                for (int i = 0; i < 8; i++)
#pragma unroll
                    for (int j = 0; j < 4; j++)
#pragma unroll
                        for (int r = 0; r < 4; r++) {
                            float v = acc[i][j][r] + bv[j];
                            if (p == 2) v = __fdividef(1.0f, 1.0f + __expf(-v));
                            int row = i * 16 + quad * 4 + r;
                            int col = wn + j * 16 + fr;
                            S[row * 136 + col] = f2b(v);
                        }
            }
            __syncthreads();
#pragma unroll
            for (int rep = 0; rep < 8; rep++) {
                int row = rep * 16 + (tid >> 4), ch = tid & 15;
                uint4 val = *(const uint4*)(S + row * 136 + ch * 8);
                *(uint4*)(Y + (size_t)(m0 + h * 128 + row) * 1024 + n0 + ch * 8) = val;
            }
        }
    } else {
        float* Sf = (float*)pool;                // [64][132] f32 per quarter
#pragma unroll
        for (int h = 0; h < 2; h++)
#pragma unroll
            for (int ih = 0; ih < 2; ih++) {
                __syncthreads();
                if ((w >> 1) == h) {
#pragma unroll
                    for (int ii = 0; ii < 4; ii++)
#pragma unroll
                        for (int j = 0; j < 4; j++)
#pragma unroll
                            for (int r = 0; r < 4; r++) {
                                int row = ii * 16 + quad * 4 + r;
                                int col = wn + j * 16 + fr;
                                Sf[row * 132 + col] = acc[ih * 4 + ii][j][r];
                            }
                }
                __syncthreads();
#pragma unroll
                for (int rep = 0; rep < 8; rep++) {
                    int row = rep * 8 + (tid >> 5), ch = tid & 31;
                    f4 val = *(const f4*)(Sf + row * 132 + ch * 4);
                    *(f4*)(Yf + (size_t)(m0 + h * 128 + ih * 64 + row) * 1024 + n0 + ch * 4) = val;
                }
            }
    }
}

// ---------------- fused prep: convx | prepw | bias3, grid-partitioned ----------------
__global__ __launch_bounds__(256) void prep_all(
    const float* __restrict__ x, const float* __restrict__ lastx,
    const float* __restrict__ Wk, const float* __restrict__ Wv,
    const float* __restrict__ Wr, const float* __restrict__ Wo,
    const float* __restrict__ tmk, const float* __restrict__ tmv, const float* __restrict__ tmr,
    u16* __restrict__ xb, u16* __restrict__ Wall, float* __restrict__ bias)
{
    int b = blockIdx.x;
    if (b < 16384) {
        int e = (b * 256 + threadIdx.x) << 2;
        f4 v = *(const f4*)(x + e);
        *(uint2*)(xb + e) = make_uint2(cvt2bf(v.x, v.y), cvt2bf(v.z, v.w));
    } else if (b < 20480) {
        int e = ((b - 16384) * 256 + threadIdx.x) << 2;
        int wid = e >> 20;
        int off = e & 1048575;
        int c = e & 1023;
        const float* src = wid == 0 ? Wk : (wid == 1 ? Wv : (wid == 2 ? Wr : Wo));
        f4 v = *(const f4*)(src + off);
        if (wid < 3) {
            const float* m = wid == 0 ? tmk : (wid == 1 ? tmv : tmr);
            v = v * *(const f4*)(m + c);
        }
        *(uint2*)(Wall + e) = make_uint2(cvt2bf(v.x, v.y), cvt2bf(v.z, v.w));
    } else {
        int wid = (b - 20480) * 4 + (threadIdx.x >> 6);
        int lane = threadIdx.x & 63;
        int proj = wid >> 10;
        int n = wid & 1023;
        const float* W = proj == 0 ? Wk : (proj == 1 ? Wv : Wr);
        const float* m = proj == 0 ? tmk : (proj == 1 ? tmv : tmr);
        float acc[8];
#pragma unroll
        for (int bb = 0; bb < 8; bb++) acc[bb] = 0.f;
        for (int c = lane; c < 1024; c += 64) {
            float wc = W[n * 1024 + c] * (1.0f - m[c]);
#pragma unroll
            for (int bb = 0; bb < 8; bb++) acc[bb] = fmaf(lastx[bb * 1024 + c], wc, acc[bb]);
        }
#pragma unroll
        for (int bb = 0; bb < 8; bb++) {
            float v = acc[bb];
#pragma unroll
            for (int sh = 32; sh >= 1; sh >>= 1) v += __shfl_xor(v, sh);
            if (lane == 0) bias[proj * 8192 + bb * 1024 + n] = v;
        }
    }
}

// ---------------- chunked wkv scan: T=2048 = 64 chunks x 32; 2 channels/thread ----------------
__global__ __launch_bounds__(256) void wkv_pass1(
    const u16* __restrict__ Kp, const u16* __restrict__ Vp,
    const float* __restrict__ tdec,
    float* __restrict__ Ca, float* __restrict__ Cb, float* __restrict__ Ce)
{
    int tid = blockIdx.x * 256 + threadIdx.x;
    int c = (tid & 511) << 1;
    int chunk = (tid >> 9) & 63;
    int n = tid >> 15;
    float w0 = __expf(tdec[c]), w1 = __expf(tdec[c + 1]);
    int base = (n * 2048 + chunk * 32) * 1024 + c;
    float a0 = 0.f, b0 = 0.f, e0 = -1e30f;
    float a1 = 0.f, b1 = 0.f, e1 = -1e30f;
#pragma unroll 4
    for (int i = 0; i < 32; i++) {
        u32 ku = *(const u32*)(Kp + base + (i << 10));
        u32 vu = *(const u32*)(Vp + base + (i << 10));
        float k0 = b2f((u16)ku), k1 = b2f((u16)(ku >> 16));
        float v0 = b2f((u16)vu), v1 = b2f((u16)(vu >> 16));
        float en0 = fmaxf(e0 - w0, k0);
        float f10 = __expf(e0 - w0 - en0), f20 = __expf(k0 - en0);
        a0 = fmaf(f10, a0, f20 * v0); b0 = fmaf(f10, b0, f20); e0 = en0;
        float en1 = fmaxf(e1 - w1, k1);
        float f11 = __expf(e1 - w1 - en1), f21 = __expf(k1 - en1);
        a1 = fmaf(f11, a1, f21 * v1); b1 = fmaf(f11, b1, f21); e1 = en1;
    }
    int oidx = ((n * 64 + chunk) << 10) + c;
    *(float2*)(Ca + oidx) = make_float2(a0, a1);
    *(float2*)(Cb + oidx) = make_float2(b0, b1);
    *(float2*)(Ce + oidx) = make_float2(e0, e1);
}

// In-place: overwrites chunk summaries with chunk-start prefixes.
__global__ __launch_bounds__(256) void wkv_pass2(
    const float* __restrict__ state, const float* __restrict__ tdec,
    float* Ca, float* Cb, float* Ce)
{
    int tid = blockIdx.x * 256 + threadIdx.x;
    int c = tid & 1023;
    int n = tid >> 10;
    float a = state[(n * 3 + 0) * 1024 + c];
    float b = state[(n * 3 + 1) * 1024 + c];
    float e = state[(n * 3 + 2) * 1024 + c];
    float wL = __expf(tdec[c]) * 32.0f;
    for (int ch = 0; ch < 64; ++ch) {
        int idx = ((n * 64 + ch) << 10) + c;
        float ca = Ca[idx], cb = Cb[idx], ce = Ce[idx];
        Ca[idx] = a; Cb[idx] = b; Ce[idx] = e;
        float en = fmaxf(e - wL, ce);
        float f1 = __expf(e - wL - en);
        float f2 = __expf(ce - en);
        a = fmaf(f1, a, f2 * ca);
        b = fmaf(f1, b, f2 * cb);
        e = en;
    }
}

__global__ __launch_bounds__(256) void wkv_pass3(
    const u16* __restrict__ Kp, const u16* __restrict__ Vp, const u16* __restrict__ SRp,
    const float* __restrict__ Sa, const float* __restrict__ Sb, const float* __restrict__ Se,
    const float* __restrict__ tfirst, const float* __restrict__ tdec,
    u16* __restrict__ Pp)
{
    int tid = blockIdx.x * 256 + threadIdx.x;
    int c = (tid & 511) << 1;
    int chunk = (tid >> 9) & 63;
    int n = tid >> 15;
    int sidx = ((n * 64 + chunk) << 10) + c;
    float a0 = Sa[sidx], b0 = Sb[sidx], e0 = Se[sidx];
    float a1 = Sa[sidx + 1], b1 = Sb[sidx + 1], e1 = Se[sidx + 1];
    float u0 = tfirst[c], u1 = tfirst[c + 1];
    float w0 = __expf(tdec[c]), w1 = __expf(tdec[c + 1]);
    int base = (n * 2048 + chunk * 32) * 1024 + c;
#pragma unroll 2
    for (int i = 0; i < 32; i++) {
        u32 ku = *(const u32*)(Kp + base + (i << 10));
        u32 vu = *(const u32*)(Vp + base + (i << 10));
        u32 su = *(const u32*)(SRp + base + (i << 10));
        float k0 = b2f((u16)ku), k1 = b2f((u16)(ku >> 16));
        float v0 = b2f((u16)vu), v1 = b2f((u16)(vu >> 16));
        float s0 = b2f((u16)su), s1 = b2f((u16)(su >> 16));
        float t0 = fmaxf(u0 + k0, e0);
        float x10 = __expf(e0 - t0), x20 = __expf(u0 + k0 - t0);
        float wkv0 = __fdividef(fmaf(x10, a0, x20 * v0), fmaf(x10, b0, x20));
        float t1 = fmaxf(u1 + k1, e1);
        float x11 = __expf(e1 - t1), x21 = __expf(u1 + k1 - t1);
        float wkv1 = __fdividef(fmaf(x11, a1, x21 * v1), fmaf(x11, b1, x21));
        *(u32*)(Pp + base + (i << 10)) = (u32)f2b(wkv0 * s0) | ((u32)f2b(wkv1 * s1) << 16);
        float en0 = fmaxf(e0 - w0, k0);
        float f10 = __expf(e0 - w0 - en0), f20 = __expf(k0 - en0);
        a0 = fmaf(f10, a0, f20 * v0); b0 = fmaf(f10, b0, f20); e0 = en0;
        float en1 = fmaxf(e1 - w1, k1);
        float f11 = __expf(e1 - w1 - en1), f21 = __expf(k1 - en1);
        a1 = fmaf(f11, a1, f21 * v1); b1 = fmaf(f11, b1, f21); e1 = en1;
    }
}

extern "C" void kernel_launch(void* const* d_in, const int* in_sizes, int n_in,
                              void* d_out, int out_size, void* d_ws, size_t ws_size,
                              hipStream_t stream) {
    const float* x      = (const float*)d_in[0];
    const float* Wk     = (const float*)d_in[2];
    const float* Wv     = (const float*)d_in[3];
    const float* Wr     = (const float*)d_in[4];
    const float* Wo     = (const float*)d_in[5];
    const float* tmk    = (const float*)d_in[6];
    const float* tmv    = (const float*)d_in[7];
    const float* tmr    = (const float*)d_in[8];
    const float* tdec   = (const float*)d_in[9];
    const float* tfirst = (const float*)d_in[10];
    const float* lastx  = (const float*)d_in[11];
    const float* state  = (const float*)d_in[12];
    float* out = (float*)d_out;

    const size_t MB = 1024ull * 1024ull;
    char* ws = (char*)d_ws;
    u16* Kb   = (u16*)(ws);                  // 32 MB
    u16* Vb   = (u16*)(ws + 32 * MB);        // 32 MB
    u16* SRb  = (u16*)(ws + 64 * MB);        // 32 MB
    u16* xb   = (u16*)(ws + 96 * MB);        // 32 MB; reused as P after gemm
    u16* Wall = (u16*)(ws + 128 * MB);       // 8 MB
    float* bias = (float*)(ws + 136 * MB);   // 96 KB
    float* Ca = (float*)(ws + 137 * MB);     // 2 MB each (64 chunks)
    float* Cb = (float*)(ws + 139 * MB);
    float* Ce = (float*)(ws + 141 * MB);
    u16* Pb = xb;

    dim3 blk(256);
    prep_all<<<21248, blk, 0, stream>>>(x, lastx, Wk, Wv, Wr, Wo, tmk, tmv, tmr, xb, Wall, bias);
    gemm_ts<0><<<dim3(1536), blk, 0, stream>>>(xb, Wall, bias, Kb, Vb, SRb, nullptr);
    wkv_pass1<<<1024, blk, 0, stream>>>(Kb, Vb, tdec, Ca, Cb, Ce);
    wkv_pass2<<<32, blk, 0, stream>>>(state, tdec, Ca, Cb, Ce);
    wkv_pass3<<<1024, blk, 0, stream>>>(Kb, Vb, SRb, Ca, Cb, Ce, tfirst, tdec, Pb);
    gemm_ts<1><<<dim3(512), blk, 0, stream>>>(Pb, Wall + 3145728, nullptr,
                                              nullptr, nullptr, nullptr, out);
}

// Round 5
// 345.052 us; speedup vs baseline: 1.0969x; 1.0969x over previous
//
#include <hip/hip_runtime.h>
#include <hip/hip_bf16.h>
#include <stdint.h>

// RWKV TimeMixing: N=8, T=2048, C=1024.
// Round 10: R9 with the two wkv_pass2 beta-content bugs fixed (group aggregate
// and rescan absorbed chunk summaries with beta content 1 instead of cb[i]).
// GEMMs = R7 verbatim (measured best: kvr 118.8us). wkv_pass2 = two-level scan
// (8 chunks/thread in regs + shfl-scan of group maps); pass1/3 = 4 ch/thread.

typedef float f4 __attribute__((ext_vector_type(4)));
typedef short bh8 __attribute__((ext_vector_type(8)));
typedef unsigned int u32;
typedef unsigned short u16;

__device__ __forceinline__ u32 cvt2bf(float a, float b) {
    __hip_bfloat162 h = __float22bfloat162_rn(make_float2(a, b));
    u32 u; __builtin_memcpy(&u, &h, 4); return u;
}
__device__ __forceinline__ float b2f(u16 u) {
    u32 x = (u32)u << 16; float f; __builtin_memcpy(&f, &x, 4); return f;
}
__device__ __forceinline__ u16 f2b(float f) {
    __hip_bfloat16 h = __float2bfloat16(f);
    u16 u; __builtin_memcpy(&u, &h, 2); return u;
}
__device__ __forceinline__ void gld_lds16(const void* g, void* l) {
    __builtin_amdgcn_global_load_lds(
        (const __attribute__((address_space(1))) u32*)g,
        (__attribute__((address_space(3))) u32*)l, 16, 0, 0);
}

// ---------------------------------------------------------------------------
// gemm256<EPI> — R7 verbatim. 256x256/BK=64/8-wave 8-phase, counted vmcnt,
// chunk-XOR LDS swizzle, s_setprio, XCD-locality block decode.
// ---------------------------------------------------------------------------

#define BAR() __builtin_amdgcn_s_barrier()

#define PH_MFMA(I0, J0) \
  BAR(); \
  asm volatile("s_waitcnt lgkmcnt(0)" ::: "memory"); \
  __builtin_amdgcn_s_setprio(1); \
  _Pragma("unroll") for (int ks = 0; ks < 2; ks++) \
  _Pragma("unroll") for (int i = 0; i < 4; i++) \
  _Pragma("unroll") for (int j = 0; j < 2; j++) \
    acc[(I0)+i][(J0)+j] = __builtin_amdgcn_mfma_f32_16x16x32_bf16( \
        af[i][ks], bf[(J0)+j][ks], acc[(I0)+i][(J0)+j], 0, 0, 0); \
  __builtin_amdgcn_s_setprio(0);

#define GBODY(cA, cB, nA, nB, KKN, STG) do { \
  const u16* ap0 = (cA) + (wm + fr) * 64 + cs0; \
  const u16* ap1 = (cA) + (wm + fr) * 64 + (cs0 ^ 32); \
  const u16* bp0 = (cB) + (wn + fr) * 64 + cs0; \
  const u16* bp1 = (cB) + (wn + fr) * 64 + (cs0 ^ 32); \
  bh8 af[4][2], bf[4][2]; \
  /* ph1 */ \
  _Pragma("unroll") for (int i = 0; i < 4; i++) { \
    af[i][0] = *(const bh8*)(ap0 + i * 1024); af[i][1] = *(const bh8*)(ap1 + i * 1024); } \
  _Pragma("unroll") for (int j = 0; j < 2; j++) { \
    bf[j][0] = *(const bh8*)(bp0 + j * 1024); bf[j][1] = *(const bh8*)(bp1 + j * 1024); } \
  if (STG) { \
    gld_lds16(gB + srcB_lane + (KKN),                 (nB) + w * 1024); \
    gld_lds16(gB + srcB_lane + 8192 + (KKN),          (nB) + w * 1024 + 512); \
    gld_lds16(gB + srcB_lane + 131072 + (KKN),        (nB) + 8192 + w * 1024); \
    gld_lds16(gB + srcB_lane + 131072 + 8192 + (KKN), (nB) + 8192 + w * 1024 + 512); } \
  PH_MFMA(0, 0); \
  BAR(); \
  /* ph2 */ \
  _Pragma("unroll") for (int j = 0; j < 2; j++) { \
    bf[2 + j][0] = *(const bh8*)(bp0 + (2 + j) * 1024); bf[2 + j][1] = *(const bh8*)(bp1 + (2 + j) * 1024); } \
  if (STG) { \
    gld_lds16(gA + srcA_lane + (KKN),          (nA) + w * 512); \
    gld_lds16(gA + srcA_lane + 131072 + (KKN), (nA) + 8192 + w * 512); } \
  PH_MFMA(0, 2); \
  if (STG) { asm volatile("s_waitcnt vmcnt(6)" ::: "memory"); } \
  else     { asm volatile("s_waitcnt vmcnt(0)" ::: "memory"); } \
  BAR(); \
  /* ph3 */ \
  _Pragma("unroll") for (int i = 0; i < 4; i++) { \
    af[i][0] = *(const bh8*)(ap0 + (4 + i) * 1024); af[i][1] = *(const bh8*)(ap1 + (4 + i) * 1024); } \
  if (STG) gld_lds16(gA + srcA_lane + 65536 + (KKN), (nA) + 4096 + w * 512); \
  PH_MFMA(4, 0); \
  BAR(); \
  /* ph4 (no ds_reads; bf held) */ \
  if (STG) gld_lds16(gA + srcA_lane + 131072 + 65536 + (KKN), (nA) + 12288 + w * 512); \
  PH_MFMA(4, 2); \
  if (STG) { asm volatile("s_waitcnt vmcnt(2)" ::: "memory"); } \
  BAR(); \
} while (0)

template<int EPI>
__global__ __launch_bounds__(512, 2) void gemm256(
    const u16* __restrict__ Ag, const u16* __restrict__ Bg, const float* __restrict__ bias,
    u16* __restrict__ Kb, u16* __restrict__ Vb, u16* __restrict__ SRb, float* __restrict__ Yf)
{
    __shared__ __align__(16) char pool[131072];
    u16* A0s = (u16*)pool;
    u16* B0s = A0s + 16384;
    u16* A1s = B0s + 16384;
    u16* B1s = A1s + 16384;

    const int bid = blockIdx.x;
    const int xcd = bid & 7;
    const int s   = bid >> 3;
    int p, mt, nt;
    if (EPI == 0) { p = s >> 5; int r = s & 31; nt = r & 3; mt = xcd * 8 + (r >> 2); }
    else          { p = 0;                      nt = s & 3; mt = xcd * 8 + (s >> 2); }
    const int n0 = nt * 256;
    const int m0 = mt * 256;

    const u16* gA = Ag + (size_t)m0 * 1024;
    const u16* gB = Bg + (EPI == 0 ? (size_t)p * 1048576 : 0) + (size_t)n0 * 1024;

    const int tid  = threadIdx.x;
    const int w    = tid >> 6;
    const int lane = tid & 63;
    const int wr = w >> 2, wc = w & 3;
    const int wm = wr * 128, wn = wc * 64;
    const int fr = lane & 15, quad = lane >> 4;
    const int cs0 = (quad ^ (fr & 7)) * 8;

    const int l8 = lane >> 3, l7 = lane & 7;
    const int chs = (l7 ^ l8) * 8;
    const int srcA_lane = (w * 8 + l8) * 1024 + chs;
    const int srcB_lane = (w * 16 + l8) * 1024 + chs;

    f4 acc[8][4];
#pragma unroll
    for (int i = 0; i < 8; i++)
#pragma unroll
        for (int j = 0; j < 4; j++) { f4 z = {0.f, 0.f, 0.f, 0.f}; acc[i][j] = z; }

#pragma unroll
    for (int q = 0; q < 4; q++)
        gld_lds16(gA + srcA_lane + q * 65536, A0s + q * 4096 + w * 512);
#pragma unroll
    for (int H = 0; H < 2; H++)
#pragma unroll
        for (int c = 0; c < 2; c++)
            gld_lds16(gB + srcB_lane + H * 131072 + c * 8192, B0s + H * 8192 + w * 1024 + c * 512);
    asm volatile("s_waitcnt vmcnt(0)" ::: "memory");
    BAR();

    for (int t = 0; t < 14; t += 2) {
        GBODY(A0s, B0s, A1s, B1s, (t + 1) * 64, true);
        GBODY(A1s, B1s, A0s, B0s, (t + 2) * 64, true);
    }
    GBODY(A0s, B0s, A1s, B1s, 15 * 64, true);
    GBODY(A1s, B1s, A0s, B0s, 0, false);

    if constexpr (EPI == 0) {
        const int batch = m0 >> 11;
        float bv[4];
#pragma unroll
        for (int j = 0; j < 4; j++) bv[j] = bias[p * 8192 + batch * 1024 + n0 + wn + j * 16 + fr];
        __syncthreads();
        u16* S = (u16*)pool;
#pragma unroll
        for (int i = 0; i < 8; i++)
#pragma unroll
            for (int j = 0; j < 4; j++)
#pragma unroll
                for (int r = 0; r < 4; r++) {
                    float v = acc[i][j][r] + bv[j];
                    if (p == 2) v = __fdividef(1.0f, 1.0f + __expf(-v));
                    int row = wm + i * 16 + quad * 4 + r;
                    int col = wn + j * 16 + fr;
                    int phys = (col >> 3) ^ (quad << 3);
                    S[row * 256 + phys * 8 + (col & 7)] = f2b(v);
                }
        __syncthreads();
        u16* Y = p == 0 ? Kb : (p == 1 ? Vb : SRb);
#pragma unroll
        for (int rep = 0; rep < 16; rep++) {
            int cid = rep * 512 + tid;
            int row = cid >> 5, ch = cid & 31;
            int phys = ch ^ (((row >> 2) & 3) << 3);
            uint4 val = *(const uint4*)(S + row * 256 + phys * 8);
            *(uint4*)(Y + (size_t)(m0 + row) * 1024 + n0 + ch * 8) = val;
        }
    } else {
        float* Sf = (float*)pool;
#pragma unroll
        for (int h = 0; h < 2; h++) {
            __syncthreads();
            if (wr == h) {
#pragma unroll
                for (int i = 0; i < 8; i++)
#pragma unroll
                    for (int j = 0; j < 4; j++)
#pragma unroll
                        for (int r = 0; r < 4; r++) {
                            int row = i * 16 + quad * 4 + r;
                            int col = wn + j * 16 + fr;
                            int phys = (col >> 2) ^ (quad << 4);
                            Sf[row * 256 + phys * 4 + (col & 3)] = acc[i][j][r];
                        }
            }
            __syncthreads();
#pragma unroll
            for (int rep = 0; rep < 16; rep++) {
                int cid = rep * 512 + tid;
                int row = cid >> 6, ch = cid & 63;
                int phys = ch ^ (((row >> 2) & 3) << 4);
                f4 val = *(const f4*)(Sf + row * 256 + phys * 4);
                *(f4*)(Yf + (size_t)(m0 + h * 128 + row) * 1024 + n0 + ch * 4) = val;
            }
        }
    }
}

// ---------------- fused prep: convx | prepw | bias3, grid-partitioned ----------------
__global__ __launch_bounds__(256) void prep_all(
    const float* __restrict__ x, const float* __restrict__ lastx,
    const float* __restrict__ Wk, const float* __restrict__ Wv,
    const float* __restrict__ Wr, const float* __restrict__ Wo,
    const float* __restrict__ tmk, const float* __restrict__ tmv, const float* __restrict__ tmr,
    u16* __restrict__ xb, u16* __restrict__ Wall, float* __restrict__ bias)
{
    int b = blockIdx.x;
    if (b < 16384) {
        int e = (b * 256 + threadIdx.x) << 2;
        f4 v = *(const f4*)(x + e);
        *(uint2*)(xb + e) = make_uint2(cvt2bf(v.x, v.y), cvt2bf(v.z, v.w));
    } else if (b < 20480) {
        int e = ((b - 16384) * 256 + threadIdx.x) << 2;
        int wid = e >> 20;
        int off = e & 1048575;
        int c = e & 1023;
        const float* src = wid == 0 ? Wk : (wid == 1 ? Wv : (wid == 2 ? Wr : Wo));
        f4 v = *(const f4*)(src + off);
        if (wid < 3) {
            const float* m = wid == 0 ? tmk : (wid == 1 ? tmv : tmr);
            v = v * *(const f4*)(m + c);
        }
        *(uint2*)(Wall + e) = make_uint2(cvt2bf(v.x, v.y), cvt2bf(v.z, v.w));
    } else {
        int wid = (b - 20480) * 4 + (threadIdx.x >> 6);
        int lane = threadIdx.x & 63;
        int proj = wid >> 10;
        int n = wid & 1023;
        const float* W = proj == 0 ? Wk : (proj == 1 ? Wv : Wr);
        const float* m = proj == 0 ? tmk : (proj == 1 ? tmv : tmr);
        float acc[8];
#pragma unroll
        for (int bb = 0; bb < 8; bb++) acc[bb] = 0.f;
        for (int c = lane; c < 1024; c += 64) {
            float wc = W[n * 1024 + c] * (1.0f - m[c]);
#pragma unroll
            for (int bb = 0; bb < 8; bb++) acc[bb] = fmaf(lastx[bb * 1024 + c], wc, acc[bb]);
        }
#pragma unroll
        for (int bb = 0; bb < 8; bb++) {
            float v = acc[bb];
#pragma unroll
            for (int sh = 32; sh >= 1; sh >>= 1) v += __shfl_xor(v, sh);
            if (lane == 0) bias[proj * 8192 + bb * 1024 + n] = v;
        }
    }
}

// ---------------- wkv pass1: 4 channels/thread, grid 512 ----------------
__global__ __launch_bounds__(256) void wkv_pass1(
    const u16* __restrict__ Kp, const u16* __restrict__ Vp,
    const float* __restrict__ tdec,
    float* __restrict__ Ca, float* __restrict__ Cb, float* __restrict__ Ce)
{
    int tid = blockIdx.x * 256 + threadIdx.x;
    int c = (tid & 255) << 2;
    int chunk = (tid >> 8) & 63;
    int n = tid >> 14;
    float w[4], a[4], b[4], e[4];
    f4 td = *(const f4*)(tdec + c);
#pragma unroll
    for (int j = 0; j < 4; j++) { w[j] = __expf(td[j]); a[j] = 0.f; b[j] = 0.f; e[j] = -1e30f; }
    int base = (n * 2048 + chunk * 32) * 1024 + c;
#pragma unroll 2
    for (int i = 0; i < 32; i++) {
        uint2 ku = *(const uint2*)(Kp + base + (i << 10));
        uint2 vu = *(const uint2*)(Vp + base + (i << 10));
        float k[4] = { b2f((u16)ku.x), b2f((u16)(ku.x >> 16)), b2f((u16)ku.y), b2f((u16)(ku.y >> 16)) };
        float v[4] = { b2f((u16)vu.x), b2f((u16)(vu.x >> 16)), b2f((u16)vu.y), b2f((u16)(vu.y >> 16)) };
#pragma unroll
        for (int j = 0; j < 4; j++) {
            float en = fmaxf(e[j] - w[j], k[j]);
            float f1 = __expf(e[j] - w[j] - en), f2 = __expf(k[j] - en);
            a[j] = fmaf(f1, a[j], f2 * v[j]); b[j] = fmaf(f1, b[j], f2); e[j] = en;
        }
    }
    int oidx = ((n * 64 + chunk) << 10) + c;
    *(f4*)(Ca + oidx) = f4{a[0], a[1], a[2], a[3]};
    *(f4*)(Cb + oidx) = f4{b[0], b[1], b[2], b[3]};
    *(f4*)(Ce + oidx) = f4{e[0], e[1], e[2], e[3]};
}

// ---------------- wkv pass2: two-level scan, grid 256 ----------------
// Thread (n,c,g): owns chunks g*8..g*8+7 (summaries in regs). Build group map
// (A,B,E) with decay D=8*wL; shfl-up Hillis-Steele scan composes the 8 group
// maps per (n,c); apply exclusive prefix map to init state; rescan 8 chunks
// writing chunk-start prefixes in-place. Serial depth ~19 vs 64.
__global__ __launch_bounds__(256) void wkv_pass2(
    const float* __restrict__ state, const float* __restrict__ tdec,
    float* Ca, float* Cb, float* Ce)
{
    int t = blockIdx.x * 256 + threadIdx.x;
    int g = t & 7;
    int nc = t >> 3;
    int c = nc & 1023;
    int n = nc >> 10;
    float wL = __expf(tdec[c]) * 32.0f;

    float ca[8], cb[8], ce[8];
    int base = ((n * 64 + g * 8) << 10) + c;
#pragma unroll
    for (int i = 0; i < 8; i++) {
        ca[i] = Ca[base + (i << 10)];
        cb[i] = Cb[base + (i << 10)];
        ce[i] = Ce[base + (i << 10)];
    }

    // group aggregate map (content part), decay = 8*wL
    float ga = 0.f, gb = 0.f, ge = -1e30f;
#pragma unroll
    for (int i = 0; i < 8; i++) {
        float en = fmaxf(ge - wL, ce[i]);
        float f1 = __expf(ge - wL - en), f2 = __expf(ce[i] - en);
        ga = fmaf(f1, ga, f2 * ca[i]); gb = fmaf(f1, gb, f2 * cb[i]); ge = en;
    }

    // inclusive scan of maps across the 8 lanes of this (n,c)
    float ia = ga, ib = gb, ie = ge, id = wL * 8.0f;
#pragma unroll
    for (int sdist = 1; sdist < 8; sdist <<= 1) {
        float pa = __shfl_up(ia, sdist, 8);
        float pb = __shfl_up(ib, sdist, 8);
        float pe = __shfl_up(ie, sdist, 8);
        float pd = __shfl_up(id, sdist, 8);
        if (g >= sdist) {
            // compose: (current map) o (prev map): push prev's content through current
            float en = fmaxf(pe - id, ie);
            float f1 = __expf(pe - id - en), f2 = __expf(ie - en);
            ia = fmaf(f1, pa, f2 * ia); ib = fmaf(f1, pb, f2 * ib); ie = en;
            id = pd + id;
        }
    }
    // exclusive prefix map (groups 0..g-1)
    float xa = __shfl_up(ia, 1, 8), xb = __shfl_up(ib, 1, 8);
    float xe = __shfl_up(ie, 1, 8), xd = __shfl_up(id, 1, 8);

    float a0 = state[(n * 3 + 0) * 1024 + c];
    float b0 = state[(n * 3 + 1) * 1024 + c];
    float e0 = state[(n * 3 + 2) * 1024 + c];
    float sa, sb, se;
    if (g == 0) { sa = a0; sb = b0; se = e0; }
    else {
        float en = fmaxf(e0 - xd, xe);
        float f1 = __expf(e0 - xd - en), f2 = __expf(xe - en);
        sa = fmaf(f1, a0, f2 * xa); sb = fmaf(f1, b0, f2 * xb); se = en;
    }

    // rescan: write chunk-start prefixes, then absorb chunk i
#pragma unroll
    for (int i = 0; i < 8; i++) {
        int idx = base + (i << 10);
        Ca[idx] = sa; Cb[idx] = sb; Ce[idx] = se;
        float en = fmaxf(se - wL, ce[i]);
        float f1 = __expf(se - wL - en), f2 = __expf(ce[i] - en);
        sa = fmaf(f1, sa, f2 * ca[i]); sb = fmaf(f1, sb, f2 * cb[i]); se = en;
    }
}

// ---------------- wkv pass3: 4 channels/thread, grid 512 ----------------
__global__ __launch_bounds__(256) void wkv_pass3(
    const u16* __restrict__ Kp, const u16* __restrict__ Vp, const u16* __restrict__ SRp,
    const float* __restrict__ Sa, const float* __restrict__ Sb, const float* __restrict__ Se,
    const float* __restrict__ tfirst, const float* __restrict__ tdec,
    u16* __restrict__ Pp)
{
    int tid = blockIdx.x * 256 + threadIdx.x;
    int c = (tid & 255) << 2;
    int chunk = (tid >> 8) & 63;
    int n = tid >> 14;
    int sidx = ((n * 64 + chunk) << 10) + c;
    f4 av = *(const f4*)(Sa + sidx);
    f4 bv = *(const f4*)(Sb + sidx);
    f4 ev = *(const f4*)(Se + sidx);
    f4 uv = *(const f4*)(tfirst + c);
    f4 td = *(const f4*)(tdec + c);
    float a[4], b[4], e[4], u[4], w[4];
#pragma unroll
    for (int j = 0; j < 4; j++) {
        a[j] = av[j]; b[j] = bv[j]; e[j] = ev[j]; u[j] = uv[j]; w[j] = __expf(td[j]);
    }
    int base = (n * 2048 + chunk * 32) * 1024 + c;
#pragma unroll 2
    for (int i = 0; i < 32; i++) {
        uint2 ku = *(const uint2*)(Kp + base + (i << 10));
        uint2 vu = *(const uint2*)(Vp + base + (i << 10));
        uint2 su = *(const uint2*)(SRp + base + (i << 10));
        float k[4] = { b2f((u16)ku.x), b2f((u16)(ku.x >> 16)), b2f((u16)ku.y), b2f((u16)(ku.y >> 16)) };
        float v[4] = { b2f((u16)vu.x), b2f((u16)(vu.x >> 16)), b2f((u16)vu.y), b2f((u16)(vu.y >> 16)) };
        float sg[4] = { b2f((u16)su.x), b2f((u16)(su.x >> 16)), b2f((u16)su.y), b2f((u16)(su.y >> 16)) };
        u16 o[4];
#pragma unroll
        for (int j = 0; j < 4; j++) {
            float tm = fmaxf(u[j] + k[j], e[j]);
            float x1 = __expf(e[j] - tm), x2 = __expf(u[j] + k[j] - tm);
            float wkv = __fdividef(fmaf(x1, a[j], x2 * v[j]), fmaf(x1, b[j], x2));
            o[j] = f2b(wkv * sg[j]);
            float en = fmaxf(e[j] - w[j], k[j]);
            float f1 = __expf(e[j] - w[j] - en), f2 = __expf(k[j] - en);
            a[j] = fmaf(f1, a[j], f2 * v[j]); b[j] = fmaf(f1, b[j], f2); e[j] = en;
        }
        uint2 ov;
        ov.x = (u32)o[0] | ((u32)o[1] << 16);
        ov.y = (u32)o[2] | ((u32)o[3] << 16);
        *(uint2*)(Pp + base + (i << 10)) = ov;
    }
}

extern "C" void kernel_launch(void* const* d_in, const int* in_sizes, int n_in,
                              void* d_out, int out_size, void* d_ws, size_t ws_size,
                              hipStream_t stream) {
    const float* x      = (const float*)d_in[0];
    const float* Wk     = (const float*)d_in[2];
    const float* Wv     = (const float*)d_in[3];
    const float* Wr     = (const float*)d_in[4];
    const float* Wo     = (const float*)d_in[5];
    const float* tmk    = (const float*)d_in[6];
    const float* tmv    = (const float*)d_in[7];
    const float* tmr    = (const float*)d_in[8];
    const float* tdec   = (const float*)d_in[9];
    const float* tfirst = (const float*)d_in[10];
    const float* lastx  = (const float*)d_in[11];
    const float* state  = (const float*)d_in[12];
    float* out = (float*)d_out;

    const size_t MB = 1024ull * 1024ull;
    char* ws = (char*)d_ws;
    u16* Kb   = (u16*)(ws);                  // 32 MB
    u16* Vb   = (u16*)(ws + 32 * MB);        // 32 MB
    u16* SRb  = (u16*)(ws + 64 * MB);        // 32 MB
    u16* xb   = (u16*)(ws + 96 * MB);        // 32 MB; reused as P after gemm
    u16* Wall = (u16*)(ws + 128 * MB);       // 8 MB
    float* bias = (float*)(ws + 136 * MB);   // 96 KB
    float* Ca = (float*)(ws + 137 * MB);     // 2 MB each (64 chunks)
    float* Cb = (float*)(ws + 139 * MB);
    float* Ce = (float*)(ws + 141 * MB);
    u16* Pb = xb;

    dim3 blk(256);
    prep_all<<<21248, blk, 0, stream>>>(x, lastx, Wk, Wv, Wr, Wo, tmk, tmv, tmr, xb, Wall, bias);
    gemm256<0><<<dim3(768), dim3(512), 0, stream>>>(xb, Wall, bias, Kb, Vb, SRb, nullptr);
    wkv_pass1<<<512, blk, 0, stream>>>(Kb, Vb, tdec, Ca, Cb, Ce);
    wkv_pass2<<<256, blk, 0, stream>>>(state, tdec, Ca, Cb, Ce);
    wkv_pass3<<<512, blk, 0, stream>>>(Kb, Vb, SRb, Ca, Cb, Ce, tfirst, tdec, Pb);
    gemm256<1><<<dim3(256), dim3(512), 0, stream>>>(Pb, Wall + 3145728, nullptr,
                                                    nullptr, nullptr, nullptr, out);
}